// Round 1
// 585.651 us; speedup vs baseline: 1.1714x; 1.1714x over previous
//
#include <hip/hip_runtime.h>
#include <cmath>

typedef unsigned short ushort_t;
typedef __attribute__((ext_vector_type(8))) short short8;
typedef __attribute__((ext_vector_type(4))) float f32x4;

#define D_IN   4096
#define D_OUT  4096
#define T_TOK  8192
#define E_EXP  8
#define R_RANK 16
#define KCAT   4224   // 4096 + E*R
#define SCALE_LORA 2.0f

__device__ __forceinline__ ushort_t f2bf(float f) {
    unsigned int u = __float_as_uint(f);
    u += 0x7fffu + ((u >> 16) & 1u);   // RNE
    return (ushort_t)(u >> 16);
}

// ---------------------------------------------------------------------------
// K1: Wcat[o][0:4096]=bf16(Wb[o]); Wcat[o][4096+e*16+r]=bf16(Bm[e][o][r]);
//     Abf[e*16+r][:] = bf16(A[e][r][:])
// ---------------------------------------------------------------------------
__global__ __launch_bounds__(256) void build_weights(
    const float* __restrict__ Wb, const float* __restrict__ Bm,
    const float* __restrict__ A, ushort_t* __restrict__ Wcat,
    ushort_t* __restrict__ Abf) {
    int b = blockIdx.x;
    int tid = threadIdx.x;
    if (b < D_OUT) {
        const float4* src = (const float4*)(Wb + (size_t)b * D_IN);
        ushort_t* drow = Wcat + (size_t)b * KCAT;
        for (int c4 = tid; c4 < D_IN / 4; c4 += 256) {
            float4 v = src[c4];
            ushort4 o;
            o.x = f2bf(v.x); o.y = f2bf(v.y); o.z = f2bf(v.z); o.w = f2bf(v.w);
            ((ushort4*)drow)[c4] = o;
        }
        if (tid < E_EXP * R_RANK) {
            int e = tid >> 4, r = tid & 15;
            drow[D_IN + tid] = f2bf(Bm[((size_t)e * D_OUT + b) * R_RANK + r]);
        }
    } else {
        int er = b - D_OUT;   // 0..127
        const float4* src = (const float4*)(A + (size_t)er * D_IN);
        ushort_t* drow = Abf + (size_t)er * D_IN;
        for (int c4 = tid; c4 < D_IN / 4; c4 += 256) {
            float4 v = src[c4];
            ushort4 o;
            o.x = f2bf(v.x); o.y = f2bf(v.y); o.z = f2bf(v.z); o.w = f2bf(v.w);
            ((ushort4*)drow)[c4] = o;
        }
    }
}

// ---------------------------------------------------------------------------
// K2: router + x->bf16 convert. (unchanged)
// ---------------------------------------------------------------------------
__global__ __launch_bounds__(256) void router_convert(
    const float* __restrict__ x, const float* __restrict__ Wr,
    ushort_t* __restrict__ xcat, int2* __restrict__ eids,
    float2* __restrict__ wts) {
    __shared__ float sWr[4 * D_IN];   // 64 KB: 4 experts fp32
    int tid = threadIdx.x;
    int lane = tid & 63;
    int wave = tid >> 6;
    int tbase = blockIdx.x * 16 + wave * 4;

    float acc[4][E_EXP];
#pragma unroll
    for (int tk = 0; tk < 4; tk++)
#pragma unroll
        for (int e = 0; e < E_EXP; e++) acc[tk][e] = 0.f;

#pragma unroll
    for (int half = 0; half < 2; half++) {
        __syncthreads();
        {
            const float4* wsrc = (const float4*)(Wr + (size_t)half * 4 * D_IN);
            float4* wdst = (float4*)sWr;
#pragma unroll
            for (int q = 0; q < 16; q++)
                wdst[tid + q * 256] = wsrc[tid + q * 256];
        }
        __syncthreads();

        for (int c4 = lane; c4 < D_IN / 4; c4 += 64) {
            float4 wv[4];
#pragma unroll
            for (int e4 = 0; e4 < 4; e4++)
                wv[e4] = ((const float4*)(sWr + (size_t)e4 * D_IN))[c4];
#pragma unroll
            for (int tk = 0; tk < 4; tk++) {
                int t = tbase + tk;
                float4 v = ((const float4*)(x + (size_t)t * D_IN))[c4];
                if (half == 0) {
                    ushort4 o;
                    o.x = f2bf(v.x); o.y = f2bf(v.y); o.z = f2bf(v.z); o.w = f2bf(v.w);
                    ((ushort4*)(xcat + (size_t)t * KCAT))[c4] = o;
                }
#pragma unroll
                for (int e4 = 0; e4 < 4; e4++)
                    acc[tk][half * 4 + e4] +=
                        v.x * wv[e4].x + v.y * wv[e4].y + v.z * wv[e4].z + v.w * wv[e4].w;
            }
        }
    }

#pragma unroll
    for (int tk = 0; tk < 4; tk++)
#pragma unroll
        for (int e = 0; e < E_EXP; e++) {
#pragma unroll
            for (int off = 32; off > 0; off >>= 1)
                acc[tk][e] += __shfl_xor(acc[tk][e], off, 64);
        }
    if (lane == 0) {
#pragma unroll
        for (int tk = 0; tk < 4; tk++) {
            int t = tbase + tk;
            int e0 = 0; float l0 = acc[tk][0];
#pragma unroll
            for (int e = 1; e < E_EXP; e++)
                if (acc[tk][e] > l0) { l0 = acc[tk][e]; e0 = e; }
            int e1 = -1; float l1 = -3.4e38f;
#pragma unroll
            for (int e = 0; e < E_EXP; e++)
                if (e != e0 && acc[tk][e] > l1) { l1 = acc[tk][e]; e1 = e; }
            float w0 = 1.f / (1.f + expf(l1 - l0));   // softmax+top2+renorm
            eids[t] = make_int2(e0, e1);
            wts[t] = make_float2(w0, 1.f - w0);
        }
    }
}

// ---------------------------------------------------------------------------
// K3: h-GEMM fused with v build. (unchanged)
// ---------------------------------------------------------------------------
__global__ __launch_bounds__(256) void h_gemm_v(
    const ushort_t* __restrict__ Abf, const int2* __restrict__ eids,
    const float2* __restrict__ wts, ushort_t* __restrict__ xcat) {
    __shared__ __align__(16) ushort_t lA[32 * 64];    // 4 KB
    __shared__ __align__(16) ushort_t lB[128 * 64];   // 16 KB
    int tid = threadIdx.x;
    int lane = tid & 63, wave = tid >> 6;
    int rowBase = blockIdx.x * 32;
    const ushort_t* gA = xcat + (size_t)rowBase * KCAT;

    int rA = tid >> 3;              // 0..31
    int kk = (tid & 7) * 8;         // col within BK=64
    ushort_t* dA = lA + (size_t)wave * 512;   // wave-uniform, 1 KB/wave

    f32x4 acc[2][2];
#pragma unroll
    for (int i = 0; i < 2; i++)
#pragma unroll
        for (int j = 0; j < 2; j++)
            acc[i][j] = (f32x4){0.f, 0.f, 0.f, 0.f};

    int n0 = wave * 32;
    int row16 = lane & 15, q8 = (lane >> 4) * 8;

    for (int kt = 0; kt < D_IN; kt += 64) {
        __syncthreads();
        __builtin_amdgcn_global_load_lds(
            (const __attribute__((address_space(1))) unsigned int*)(gA + (size_t)rA * KCAT + kt + kk),
            (__attribute__((address_space(3))) unsigned int*)dA, 16, 0, 0);
#pragma unroll
        for (int q = 0; q < 4; q++) {
            __builtin_amdgcn_global_load_lds(
                (const __attribute__((address_space(1))) unsigned int*)(
                    Abf + (size_t)((tid >> 3) + 32 * q) * D_IN + kt + kk),
                (__attribute__((address_space(3))) unsigned int*)(
                    lB + (size_t)q * 2048 + (size_t)wave * 512), 16, 0, 0);
        }
        __syncthreads();

        short8 af[2][2], bfrag[2][2];
#pragma unroll
        for (int i = 0; i < 2; i++)
#pragma unroll
            for (int kc = 0; kc < 2; kc++)
                af[i][kc] = *(const short8*)&lA[(i * 16 + row16) * 64 + kc * 32 + q8];
#pragma unroll
        for (int j = 0; j < 2; j++)
#pragma unroll
            for (int kc = 0; kc < 2; kc++)
                bfrag[j][kc] = *(const short8*)&lB[(n0 + j * 16 + row16) * 64 + kc * 32 + q8];
#pragma unroll
        for (int i = 0; i < 2; i++)
#pragma unroll
            for (int j = 0; j < 2; j++) {
                acc[i][j] = __builtin_amdgcn_mfma_f32_16x16x32_bf16(
                    af[i][0], bfrag[j][0], acc[i][j], 0, 0, 0);
                acc[i][j] = __builtin_amdgcn_mfma_f32_16x16x32_bf16(
                    af[i][1], bfrag[j][1], acc[i][j], 0, 0, 0);
            }
    }

#pragma unroll
    for (int i = 0; i < 2; i++) {
        int rbase = rowBase + i * 16 + (lane >> 4) * 4;
#pragma unroll
        for (int reg = 0; reg < 4; reg++) {
            int t = rbase + reg;
            int2 e = eids[t];
            float2 w = wts[t];
#pragma unroll
            for (int j = 0; j < 2; j++) {
                int c = n0 + j * 16 + (lane & 15);
                int ce = c >> 4;
                float coef = (ce == e.x) ? (SCALE_LORA * w.x)
                           : ((ce == e.y) ? (SCALE_LORA * w.y) : 0.f);
                xcat[(size_t)t * KCAT + D_IN + c] = f2bf(coef * acc[i][j][reg]);
            }
        }
    }
}

// ---------------------------------------------------------------------------
// Main GEMM: 256x256 tile, BK=64, 8 waves (2Mx4N), 8-phase schedule with
// counted vmcnt (T3+T4), st-swizzled LDS (T2, linear-dest global_load_lds +
// pre-swizzled source per rule #21), setprio around MFMA clusters (T5),
// XCD-chunked block swizzle (T1). K=4224 = 66 tiles of 64, 33 iterations.
//
// LDS: [buf][A/B][half(128 rows)][128][64] bf16 = 128 KiB, double-buffered.
// Staging schedule (each stage = 4 per-wave vmem instr; safety: a slot is
// restaged only in a phase after the end-barrier retiring its last reader):
//   S4 @P1: B(tile 2i+1)->buf1.B   (buf1.B last read P8 prev iter)
//   S1 @P4: A(tile 2i+2)->buf0.A   (buf0.A last ds_read in P3)
//   S2 @P5: B(tile 2i+2)->buf0.B   (buf0.B last ds_read in P4)
//   S3 @P8: A(tile 2i+3)->buf1.A   (buf1.A last ds_read in P7)
// Waits: vmcnt(4) at end of P4 (covers S3(i-1)+S4(i) for P5 reads) and end
// of P8 (covers S1(i)+S2(i) for next P1 reads). Never drained to 0 in-loop.
// ---------------------------------------------------------------------------
#define NKT 66
#define NIT 33

__global__ __launch_bounds__(512, 2) void gemm_bt_main(
    const ushort_t* __restrict__ Am, const ushort_t* __restrict__ Bmat,
    float* __restrict__ C, const float* __restrict__ bias) {
    __shared__ __align__(16) ushort_t lds[2][2][2][128][64];   // 128 KiB
    const int lda = KCAT, ldb = KCAT, ldc = D_OUT;
    int tid = threadIdx.x;
    int lane = tid & 63, wave = tid >> 6;
    int wm = wave >> 2, wn = wave & 3;

    // XCD swizzle: 512 blocks -> 8 contiguous chunks of 64 (8m x 8n band)
    int id = ((blockIdx.x & 7) << 6) | (blockIdx.x >> 3);
    int band = id >> 6, wi = id & 63;
    int mt = ((band >> 1) << 3) | (wi & 7);       // 0..31
    int nt = ((band & 1) << 3) | (wi >> 3);       // 0..15
    const int rowBase = mt * 256, colBase = nt * 256;

    const ushort_t* gA = Am + (size_t)rowBase * lda;
    const ushort_t* gB = Bmat + (size_t)colBase * ldb;

    // staging: linear LDS dest (lane*16B), source column pre-swizzled with the
    // same involution the reader applies: colbyte ^= ((row&7)<<4)
    const int srow = tid >> 3;                               // 0..63 (+64*q)
    const int scol = (((tid & 7) ^ (srow & 7)) << 3);        // elements

#define STAGE(MAT, SRC, LD, BUF, KT)                                           \
    {                                                                          \
        _Pragma("unroll")                                                      \
        for (int h = 0; h < 2; h++) {                                          \
            _Pragma("unroll")                                                  \
            for (int q = 0; q < 2; q++) {                                      \
                __builtin_amdgcn_global_load_lds(                              \
                    (const __attribute__((address_space(1))) unsigned int*)(   \
                        (SRC) + (size_t)(h * 128 + q * 64 + srow) * (LD) +     \
                        (KT) + scol),                                          \
                    (__attribute__((address_space(3))) unsigned int*)(         \
                        &lds[BUF][MAT][h][0][0] + q * 4096 + wave * 512),      \
                    16, 0, 0);                                                 \
            }                                                                  \
        }                                                                      \
    }

    // read-side swizzled column offsets (bytes); row&7 == lane&7 for all frags
    int cSwz[2];
#pragma unroll
    for (int kc = 0; kc < 2; kc++)
        cSwz[kc] = (kc * 64 + (lane >> 4) * 16) ^ ((lane & 7) << 4);
    const int rOff = (lane & 15) * 128;            // bytes
    const int bRow = (wn & 1) * 64 * 128;          // wave's B rows within half

    const char* baseA = (const char*)&lds[0][0][wm][0][0];
    const char* baseB = (const char*)&lds[0][1][wn >> 1][0][0];

    f32x4 acc[8][4];
#pragma unroll
    for (int i = 0; i < 8; i++)
#pragma unroll
        for (int j = 0; j < 4; j++) acc[i][j] = (f32x4){0.f, 0.f, 0.f, 0.f};

    short8 aF[4][2], bF[2][2];

#define READ_A(BUF, S)                                                         \
    _Pragma("unroll")                                                          \
    for (int m4 = 0; m4 < 4; m4++) {                                           \
        _Pragma("unroll")                                                      \
        for (int kc = 0; kc < 2; kc++)                                         \
            aF[m4][kc] = *(const short8*)(baseA + (BUF) * 65536 +              \
                ((S) * 4 + m4) * 2048 + rOff + cSwz[kc]);                      \
    }

#define READ_B(BUF, U)                                                         \
    _Pragma("unroll")                                                          \
    for (int n2 = 0; n2 < 2; n2++) {                                           \
        _Pragma("unroll")                                                      \
        for (int kc = 0; kc < 2; kc++)                                         \
            bF[n2][kc] = *(const short8*)(baseB + (BUF) * 65536 + bRow +       \
                ((U) * 2 + n2) * 2048 + rOff + cSwz[kc]);                      \
    }

#define MFMA16(S, U)                                                           \
    __builtin_amdgcn_s_setprio(1);                                             \
    _Pragma("unroll")                                                          \
    for (int m4 = 0; m4 < 4; m4++) {                                           \
        _Pragma("unroll")                                                      \
        for (int n2 = 0; n2 < 2; n2++) {                                       \
            _Pragma("unroll")                                                  \
            for (int kc = 0; kc < 2; kc++)                                     \
                acc[(S) * 4 + m4][(U) * 2 + n2] =                              \
                    __builtin_amdgcn_mfma_f32_16x16x32_bf16(                   \
                        aF[m4][kc], bF[n2][kc],                                \
                        acc[(S) * 4 + m4][(U) * 2 + n2], 0, 0, 0);             \
        }                                                                      \
    }                                                                          \
    __builtin_amdgcn_s_setprio(0);

#define MIDBAR()                                                               \
    __builtin_amdgcn_s_barrier();                                              \
    asm volatile("s_waitcnt lgkmcnt(0)" ::: "memory");

#define ENDBAR() __builtin_amdgcn_s_barrier();

    // prologue: tile0 -> buf0 (A+B), tile1 A -> buf1.A
    STAGE(0, gA, lda, 0, 0)
    STAGE(1, gB, ldb, 0, 0)
    STAGE(0, gA, lda, 1, 64)
    asm volatile("s_waitcnt vmcnt(4)" ::: "memory");   // tile0 landed
    __builtin_amdgcn_s_barrier();

    for (int it = 0; it < NIT; ++it) {
        int ktB1 = (2 * it + 1) * 64;
        int t2 = 2 * it + 2; if (t2 > NKT - 1) t2 = NKT - 1;  // clamp tail
        int t3 = 2 * it + 3; if (t3 > NKT - 1) t3 = NKT - 1;
        int kt2 = t2 * 64, kt3 = t3 * 64;

        // P1: buf0 quad (m0,n0); stage S4: B(2i+1)->buf1.B
        READ_A(0, 0) READ_B(0, 0)
        STAGE(1, gB, ldb, 1, ktB1)
        MIDBAR() MFMA16(0, 0) ENDBAR()

        // P2: buf0 quad (m0,n1)
        READ_B(0, 1)
        MIDBAR() MFMA16(0, 1) ENDBAR()

        // P3: buf0 quad (m1,n1)
        READ_A(0, 1)
        MIDBAR() MFMA16(1, 1) ENDBAR()

        // P4: buf0 quad (m1,n0); stage S1: A(2i+2)->buf0.A; counted wait
        READ_B(0, 0)
        STAGE(0, gA, lda, 0, kt2)
        MIDBAR() MFMA16(1, 0)
        asm volatile("s_waitcnt vmcnt(4)" ::: "memory");   // S3(i-1)+S4 landed
        ENDBAR()

        // P5: buf1 quad (m0,n0); stage S2: B(2i+2)->buf0.B
        READ_A(1, 0) READ_B(1, 0)
        STAGE(1, gB, ldb, 0, kt2)
        MIDBAR() MFMA16(0, 0) ENDBAR()

        // P6: buf1 quad (m0,n1)
        READ_B(1, 1)
        MIDBAR() MFMA16(0, 1) ENDBAR()

        // P7: buf1 quad (m1,n1)
        READ_A(1, 1)
        MIDBAR() MFMA16(1, 1) ENDBAR()

        // P8: buf1 quad (m1,n0); stage S3: A(2i+3)->buf1.A; counted wait
        READ_B(1, 0)
        STAGE(0, gA, lda, 1, kt3)
        MIDBAR() MFMA16(1, 0)
        asm volatile("s_waitcnt vmcnt(4)" ::: "memory");   // S1+S2 landed
        ENDBAR()
    }

    // epilogue: C/D layout col=lane&15, row=(lane>>4)*4+reg
    int r0 = rowBase + wm * 128 + (lane >> 4) * 4;
    int c0 = colBase + wn * 64 + (lane & 15);
#pragma unroll
    for (int mf = 0; mf < 8; mf++) {
#pragma unroll
        for (int nf = 0; nf < 4; nf++) {
            int cc = c0 + nf * 16;
            float badd = bias[cc];
#pragma unroll
            for (int reg = 0; reg < 4; reg++)
                C[(size_t)(r0 + mf * 16 + reg) * ldc + cc] = acc[mf][nf][reg] + badd;
        }
    }
}

// ---------------------------------------------------------------------------
extern "C" void kernel_launch(void* const* d_in, const int* in_sizes, int n_in,
                              void* d_out, int out_size, void* d_ws, size_t ws_size,
                              hipStream_t stream) {
    const float* x    = (const float*)d_in[0];   // [4,2048,4096]
    const float* Wb   = (const float*)d_in[1];   // [4096,4096]
    const float* bias = (const float*)d_in[2];   // [4096]
    const float* Wr   = (const float*)d_in[3];   // [8,4096]
    const float* A    = (const float*)d_in[4];   // [8,16,4096]
    const float* Bm   = (const float*)d_in[5];   // [8,4096,16]
    float* out = (float*)d_out;

    char* p = (char*)d_ws;
    ushort_t* xcat = (ushort_t*)p; p += (size_t)T_TOK * KCAT * 2;   // 69.2 MB
    ushort_t* Wcat = (ushort_t*)p; p += (size_t)D_OUT * KCAT * 2;   // 34.6 MB
    ushort_t* Abf  = (ushort_t*)p; p += (size_t)(E_EXP * R_RANK) * D_IN * 2; // 1 MB
    int2*     eids = (int2*)p;     p += (size_t)T_TOK * sizeof(int2);
    float2*   wts  = (float2*)p;   p += (size_t)T_TOK * sizeof(float2);

    build_weights<<<D_OUT + E_EXP * R_RANK, 256, 0, stream>>>(Wb, Bm, A, Wcat, Abf);
    router_convert<<<T_TOK / 16, 256, 0, stream>>>(x, Wr, xcat, eids, wts);
    // h = xcat[:, :4096] @ Abf^T, scaled+masked, written into xcat cols 4096+
    h_gemm_v<<<T_TOK / 32, 256, 0, stream>>>(Abf, eids, wts, xcat);
    // out[8192,4096] = xcat @ Wcat^T + bias  (K = 4224 includes LoRA fold)
    gemm_bt_main<<<(T_TOK / 256) * (D_OUT / 256), 512, 0, stream>>>(xcat, Wcat, out, bias);
}

// Round 2
// 559.754 us; speedup vs baseline: 1.2256x; 1.0463x over previous
//
#include <hip/hip_runtime.h>
#include <cmath>

typedef unsigned short ushort_t;
typedef __attribute__((ext_vector_type(8))) short short8;
typedef __attribute__((ext_vector_type(4))) float f32x4;

#define D_IN   4096
#define D_OUT  4096
#define T_TOK  8192
#define E_EXP  8
#define R_RANK 16
#define KCAT   4224   // 4096 + E*R
#define SCALE_LORA 2.0f

__device__ __forceinline__ ushort_t f2bf(float f) {
    unsigned int u = __float_as_uint(f);
    u += 0x7fffu + ((u >> 16) & 1u);   // RNE
    return (ushort_t)(u >> 16);
}

// ---------------------------------------------------------------------------
// K1: Wcat[o][0:4096]=bf16(Wb[o]); Wcat[o][4096+e*16+r]=bf16(Bm[e][o][r]);
//     Abf[e*16+r][:] = bf16(A[e][r][:])   (unchanged)
// ---------------------------------------------------------------------------
__global__ __launch_bounds__(256) void build_weights(
    const float* __restrict__ Wb, const float* __restrict__ Bm,
    const float* __restrict__ A, ushort_t* __restrict__ Wcat,
    ushort_t* __restrict__ Abf) {
    int b = blockIdx.x;
    int tid = threadIdx.x;
    if (b < D_OUT) {
        const float4* src = (const float4*)(Wb + (size_t)b * D_IN);
        ushort_t* drow = Wcat + (size_t)b * KCAT;
        for (int c4 = tid; c4 < D_IN / 4; c4 += 256) {
            float4 v = src[c4];
            ushort4 o;
            o.x = f2bf(v.x); o.y = f2bf(v.y); o.z = f2bf(v.z); o.w = f2bf(v.w);
            ((ushort4*)drow)[c4] = o;
        }
        if (tid < E_EXP * R_RANK) {
            int e = tid >> 4, r = tid & 15;
            drow[D_IN + tid] = f2bf(Bm[((size_t)e * D_OUT + b) * R_RANK + r]);
        }
    } else {
        int er = b - D_OUT;   // 0..127
        const float4* src = (const float4*)(A + (size_t)er * D_IN);
        ushort_t* drow = Abf + (size_t)er * D_IN;
        for (int c4 = tid; c4 < D_IN / 4; c4 += 256) {
            float4 v = src[c4];
            ushort4 o;
            o.x = f2bf(v.x); o.y = f2bf(v.y); o.z = f2bf(v.z); o.w = f2bf(v.w);
            ((ushort4*)drow)[c4] = o;
        }
    }
}

// ---------------------------------------------------------------------------
// K2: router + x->bf16 convert. SINGLE PASS: all 8 experts of Wr staged fp32
// in 128 KB LDS (fits 160 KB/CU); x read exactly once (was 2 passes / 2x x
// traffic). Block = 16 tokens (4 waves x 4). Router math fully fp32,
// identical per-expert summation order to the 2-pass version.
// ---------------------------------------------------------------------------
__global__ __launch_bounds__(256) void router_convert(
    const float* __restrict__ x, const float* __restrict__ Wr,
    ushort_t* __restrict__ xcat, int2* __restrict__ eids,
    float2* __restrict__ wts) {
    __shared__ float sWr[E_EXP * D_IN];   // 128 KB: all 8 experts fp32
    int tid = threadIdx.x;
    int lane = tid & 63;
    int wave = tid >> 6;
    int tbase = blockIdx.x * 16 + wave * 4;

    {   // stage Wr: 8192 float4s, 32/thread
        const float4* wsrc = (const float4*)Wr;
        float4* wdst = (float4*)sWr;
#pragma unroll
        for (int q = 0; q < 32; q++)
            wdst[tid + q * 256] = wsrc[tid + q * 256];
    }
    __syncthreads();

    float acc[4][E_EXP];
#pragma unroll
    for (int tk = 0; tk < 4; tk++)
#pragma unroll
        for (int e = 0; e < E_EXP; e++) acc[tk][e] = 0.f;

    for (int c4 = lane; c4 < D_IN / 4; c4 += 64) {
        float4 wv[E_EXP];
#pragma unroll
        for (int e = 0; e < E_EXP; e++)
            wv[e] = ((const float4*)(sWr + (size_t)e * D_IN))[c4];
#pragma unroll
        for (int tk = 0; tk < 4; tk++) {
            int t = tbase + tk;
            float4 v = ((const float4*)(x + (size_t)t * D_IN))[c4];
            ushort4 o;
            o.x = f2bf(v.x); o.y = f2bf(v.y); o.z = f2bf(v.z); o.w = f2bf(v.w);
            ((ushort4*)(xcat + (size_t)t * KCAT))[c4] = o;
#pragma unroll
            for (int e = 0; e < E_EXP; e++)
                acc[tk][e] +=
                    v.x * wv[e].x + v.y * wv[e].y + v.z * wv[e].z + v.w * wv[e].w;
        }
    }

#pragma unroll
    for (int tk = 0; tk < 4; tk++)
#pragma unroll
        for (int e = 0; e < E_EXP; e++) {
#pragma unroll
            for (int off = 32; off > 0; off >>= 1)
                acc[tk][e] += __shfl_xor(acc[tk][e], off, 64);
        }
    if (lane == 0) {
#pragma unroll
        for (int tk = 0; tk < 4; tk++) {
            int t = tbase + tk;
            int e0 = 0; float l0 = acc[tk][0];
#pragma unroll
            for (int e = 1; e < E_EXP; e++)
                if (acc[tk][e] > l0) { l0 = acc[tk][e]; e0 = e; }
            int e1 = -1; float l1 = -3.4e38f;
#pragma unroll
            for (int e = 0; e < E_EXP; e++)
                if (e != e0 && acc[tk][e] > l1) { l1 = acc[tk][e]; e1 = e; }
            float w0 = 1.f / (1.f + expf(l1 - l0));   // softmax+top2+renorm
            eids[t] = make_int2(e0, e1);
            wts[t] = make_float2(w0, 1.f - w0);
        }
    }
}

// ---------------------------------------------------------------------------
// K3: h-GEMM fused with v build — DEEP-PIPELINED REWRITE.
// Block = 32 tokens x 128 er, BK=64, grid 256. Triple-buffered LDS (60 KB),
// stage issued 2 tiles ahead, counted s_waitcnt vmcnt(10) (never 0 in-loop),
// raw s_barrier (no compiler vmcnt(0) drain), XOR-swizzled LDS (pre-swizzled
// global source + swizzled ds_read — fixes the 16-way bank conflict of the
// row-major [*][64] tile), setprio around the MFMA cluster.
// Old structure was latency-serialized: 64 iters x full load-latency drain.
// ---------------------------------------------------------------------------
__global__ __launch_bounds__(256) void h_gemm_v(
    const ushort_t* __restrict__ Abf, const int2* __restrict__ eids,
    const float2* __restrict__ wts, ushort_t* __restrict__ xcat) {
    __shared__ __align__(16) ushort_t lA[3][32 * 64];    // 12 KB
    __shared__ __align__(16) ushort_t lB[3][128 * 64];   // 48 KB
    int tid = threadIdx.x;
    int lane = tid & 63, wave = tid >> 6;
    int rowBase = blockIdx.x * 32;
    const ushort_t* gA = xcat + (size_t)rowBase * KCAT;

    // staging geometry: thread -> (row = tid>>3, colchunk = tid&7); LDS dest is
    // linear (base + lane*16B); source col pre-swizzled by the read involution
    const int srow = tid >> 3;                              // 0..31
    const int scol = (((tid & 7) ^ (srow & 7)) << 3);       // elements

#define HSTAGE(BUF, KT)                                                        \
    {                                                                          \
        __builtin_amdgcn_global_load_lds(                                      \
            (const __attribute__((address_space(1))) unsigned int*)(           \
                gA + (size_t)srow * KCAT + (KT) + scol),                       \
            (__attribute__((address_space(3))) unsigned int*)(                 \
                &lA[BUF][0] + wave * 512), 16, 0, 0);                          \
        _Pragma("unroll")                                                      \
        for (int q = 0; q < 4; q++) {                                          \
            __builtin_amdgcn_global_load_lds(                                  \
                (const __attribute__((address_space(1))) unsigned int*)(       \
                    Abf + (size_t)(srow + 32 * q) * D_IN + (KT) + scol),       \
                (__attribute__((address_space(3))) unsigned int*)(             \
                    &lB[BUF][0] + q * 2048 + wave * 512), 16, 0, 0);           \
        }                                                                      \
    }

    f32x4 acc[2][2];
#pragma unroll
    for (int i = 0; i < 2; i++)
#pragma unroll
        for (int j = 0; j < 2; j++)
            acc[i][j] = (f32x4){0.f, 0.f, 0.f, 0.f};

    int n0 = wave * 32;
    int row16 = lane & 15;
    // swizzled column byte offsets; row&7 == row16&7 for every 16-row frag
    int cSwz[2];
#pragma unroll
    for (int kc = 0; kc < 2; kc++)
        cSwz[kc] = (kc * 64 + (lane >> 4) * 16) ^ ((row16 & 7) << 4);

    // prologue: tiles 0,1 -> bufs 0,1
    HSTAGE(0, 0)
    HSTAGE(1, 64)
    asm volatile("s_waitcnt vmcnt(5)" ::: "memory");   // tile 0 landed
    __builtin_amdgcn_s_barrier();

    for (int t = 0; t < 64; ++t) {
        int cur = t % 3;
        int tn = (t + 2 < 64) ? (t + 2) : 63;          // tail: dummy re-stage
        HSTAGE((t + 2) % 3, tn * 64)
        asm volatile("s_waitcnt vmcnt(10)" ::: "memory");  // tile t landed
        __builtin_amdgcn_s_barrier();

        short8 af[2][2], bfr[2][2];
#pragma unroll
        for (int i = 0; i < 2; i++)
#pragma unroll
            for (int kc = 0; kc < 2; kc++)
                af[i][kc] = *(const short8*)((const char*)&lA[cur][0] +
                    (i * 16 + row16) * 128 + cSwz[kc]);
#pragma unroll
        for (int j = 0; j < 2; j++)
#pragma unroll
            for (int kc = 0; kc < 2; kc++)
                bfr[j][kc] = *(const short8*)((const char*)&lB[cur][0] +
                    (n0 + j * 16 + row16) * 128 + cSwz[kc]);

        __builtin_amdgcn_s_setprio(1);
#pragma unroll
        for (int i = 0; i < 2; i++)
#pragma unroll
            for (int j = 0; j < 2; j++) {
                acc[i][j] = __builtin_amdgcn_mfma_f32_16x16x32_bf16(
                    af[i][0], bfr[j][0], acc[i][j], 0, 0, 0);
                acc[i][j] = __builtin_amdgcn_mfma_f32_16x16x32_bf16(
                    af[i][1], bfr[j][1], acc[i][j], 0, 0, 0);
            }
        __builtin_amdgcn_s_setprio(0);
        __builtin_amdgcn_s_barrier();   // retire reads before buf reuse
    }

    // epilogue: C/D layout col=lane&15, row=(lane>>4)*4+reg; apply coef, write v
#pragma unroll
    for (int i = 0; i < 2; i++) {
        int rbase = rowBase + i * 16 + (lane >> 4) * 4;
#pragma unroll
        for (int reg = 0; reg < 4; reg++) {
            int t = rbase + reg;
            int2 e = eids[t];
            float2 w = wts[t];
#pragma unroll
            for (int j = 0; j < 2; j++) {
                int c = n0 + j * 16 + (lane & 15);
                int ce = c >> 4;
                float coef = (ce == e.x) ? (SCALE_LORA * w.x)
                           : ((ce == e.y) ? (SCALE_LORA * w.y) : 0.f);
                xcat[(size_t)t * KCAT + D_IN + c] = f2bf(coef * acc[i][j][reg]);
            }
        }
    }
#undef HSTAGE
}

// ---------------------------------------------------------------------------
// Main GEMM: 256x256 tile, BK=64, 8 waves (2Mx4N), 8-phase schedule with
// counted vmcnt (T3+T4), st-swizzled LDS (T2, linear-dest global_load_lds +
// pre-swizzled source per rule #21), setprio around MFMA clusters (T5),
// XCD-chunked block swizzle (T1). K=4224 = 66 tiles of 64, 33 iterations.
// UNCHANGED from round 1 (verified 264 µs, MfmaUtil 47%, 0 bank conflicts).
// ---------------------------------------------------------------------------
#define NKT 66
#define NIT 33

__global__ __launch_bounds__(512, 2) void gemm_bt_main(
    const ushort_t* __restrict__ Am, const ushort_t* __restrict__ Bmat,
    float* __restrict__ C, const float* __restrict__ bias) {
    __shared__ __align__(16) ushort_t lds[2][2][2][128][64];   // 128 KiB
    const int lda = KCAT, ldb = KCAT, ldc = D_OUT;
    int tid = threadIdx.x;
    int lane = tid & 63, wave = tid >> 6;
    int wm = wave >> 2, wn = wave & 3;

    // XCD swizzle: 512 blocks -> 8 contiguous chunks of 64 (8m x 8n band)
    int id = ((blockIdx.x & 7) << 6) | (blockIdx.x >> 3);
    int band = id >> 6, wi = id & 63;
    int mt = ((band >> 1) << 3) | (wi & 7);       // 0..31
    int nt = ((band & 1) << 3) | (wi >> 3);       // 0..15
    const int rowBase = mt * 256, colBase = nt * 256;

    const ushort_t* gA = Am + (size_t)rowBase * lda;
    const ushort_t* gB = Bmat + (size_t)colBase * ldb;

    const int srow = tid >> 3;                               // 0..63 (+64*q)
    const int scol = (((tid & 7) ^ (srow & 7)) << 3);        // elements

#define STAGE(MAT, SRC, LD, BUF, KT)                                           \
    {                                                                          \
        _Pragma("unroll")                                                      \
        for (int h = 0; h < 2; h++) {                                          \
            _Pragma("unroll")                                                  \
            for (int q = 0; q < 2; q++) {                                      \
                __builtin_amdgcn_global_load_lds(                              \
                    (const __attribute__((address_space(1))) unsigned int*)(   \
                        (SRC) + (size_t)(h * 128 + q * 64 + srow) * (LD) +     \
                        (KT) + scol),                                          \
                    (__attribute__((address_space(3))) unsigned int*)(         \
                        &lds[BUF][MAT][h][0][0] + q * 4096 + wave * 512),      \
                    16, 0, 0);                                                 \
            }                                                                  \
        }                                                                      \
    }

    int cSwz[2];
#pragma unroll
    for (int kc = 0; kc < 2; kc++)
        cSwz[kc] = (kc * 64 + (lane >> 4) * 16) ^ ((lane & 7) << 4);
    const int rOff = (lane & 15) * 128;            // bytes
    const int bRow = (wn & 1) * 64 * 128;          // wave's B rows within half

    const char* baseA = (const char*)&lds[0][0][wm][0][0];
    const char* baseB = (const char*)&lds[0][1][wn >> 1][0][0];

    f32x4 acc[8][4];
#pragma unroll
    for (int i = 0; i < 8; i++)
#pragma unroll
        for (int j = 0; j < 4; j++) acc[i][j] = (f32x4){0.f, 0.f, 0.f, 0.f};

    short8 aF[4][2], bF[2][2];

#define READ_A(BUF, S)                                                         \
    _Pragma("unroll")                                                          \
    for (int m4 = 0; m4 < 4; m4++) {                                           \
        _Pragma("unroll")                                                      \
        for (int kc = 0; kc < 2; kc++)                                         \
            aF[m4][kc] = *(const short8*)(baseA + (BUF) * 65536 +              \
                ((S) * 4 + m4) * 2048 + rOff + cSwz[kc]);                      \
    }

#define READ_B(BUF, U)                                                         \
    _Pragma("unroll")                                                          \
    for (int n2 = 0; n2 < 2; n2++) {                                           \
        _Pragma("unroll")                                                      \
        for (int kc = 0; kc < 2; kc++)                                         \
            bF[n2][kc] = *(const short8*)(baseB + (BUF) * 65536 + bRow +       \
                ((U) * 2 + n2) * 2048 + rOff + cSwz[kc]);                      \
    }

#define MFMA16(S, U)                                                           \
    __builtin_amdgcn_s_setprio(1);                                             \
    _Pragma("unroll")                                                          \
    for (int m4 = 0; m4 < 4; m4++) {                                           \
        _Pragma("unroll")                                                      \
        for (int n2 = 0; n2 < 2; n2++) {                                       \
            _Pragma("unroll")                                                  \
            for (int kc = 0; kc < 2; kc++)                                     \
                acc[(S) * 4 + m4][(U) * 2 + n2] =                              \
                    __builtin_amdgcn_mfma_f32_16x16x32_bf16(                   \
                        aF[m4][kc], bF[n2][kc],                                \
                        acc[(S) * 4 + m4][(U) * 2 + n2], 0, 0, 0);             \
        }                                                                      \
    }                                                                          \
    __builtin_amdgcn_s_setprio(0);

#define MIDBAR()                                                               \
    __builtin_amdgcn_s_barrier();                                              \
    asm volatile("s_waitcnt lgkmcnt(0)" ::: "memory");

#define ENDBAR() __builtin_amdgcn_s_barrier();

    // prologue: tile0 -> buf0 (A+B), tile1 A -> buf1.A
    STAGE(0, gA, lda, 0, 0)
    STAGE(1, gB, ldb, 0, 0)
    STAGE(0, gA, lda, 1, 64)
    asm volatile("s_waitcnt vmcnt(4)" ::: "memory");   // tile0 landed
    __builtin_amdgcn_s_barrier();

    for (int it = 0; it < NIT; ++it) {
        int ktB1 = (2 * it + 1) * 64;
        int t2 = 2 * it + 2; if (t2 > NKT - 1) t2 = NKT - 1;  // clamp tail
        int t3 = 2 * it + 3; if (t3 > NKT - 1) t3 = NKT - 1;
        int kt2 = t2 * 64, kt3 = t3 * 64;

        // P1: buf0 quad (m0,n0); stage S4: B(2i+1)->buf1.B
        READ_A(0, 0) READ_B(0, 0)
        STAGE(1, gB, ldb, 1, ktB1)
        MIDBAR() MFMA16(0, 0) ENDBAR()

        // P2: buf0 quad (m0,n1)
        READ_B(0, 1)
        MIDBAR() MFMA16(0, 1) ENDBAR()

        // P3: buf0 quad (m1,n1)
        READ_A(0, 1)
        MIDBAR() MFMA16(1, 1) ENDBAR()

        // P4: buf0 quad (m1,n0); stage S1: A(2i+2)->buf0.A; counted wait
        READ_B(0, 0)
        STAGE(0, gA, lda, 0, kt2)
        MIDBAR() MFMA16(1, 0)
        asm volatile("s_waitcnt vmcnt(4)" ::: "memory");   // S3(i-1)+S4 landed
        ENDBAR()

        // P5: buf1 quad (m0,n0); stage S2: B(2i+2)->buf0.B
        READ_A(1, 0) READ_B(1, 0)
        STAGE(1, gB, ldb, 0, kt2)
        MIDBAR() MFMA16(0, 0) ENDBAR()

        // P6: buf1 quad (m0,n1)
        READ_B(1, 1)
        MIDBAR() MFMA16(0, 1) ENDBAR()

        // P7: buf1 quad (m1,n1)
        READ_A(1, 1)
        MIDBAR() MFMA16(1, 1) ENDBAR()

        // P8: buf1 quad (m1,n0); stage S3: A(2i+3)->buf1.A; counted wait
        READ_B(1, 0)
        STAGE(0, gA, lda, 1, kt3)
        MIDBAR() MFMA16(1, 0)
        asm volatile("s_waitcnt vmcnt(4)" ::: "memory");   // S1+S2 landed
        ENDBAR()
    }

    // epilogue: C/D layout col=lane&15, row=(lane>>4)*4+reg
    int r0 = rowBase + wm * 128 + (lane >> 4) * 4;
    int c0 = colBase + wn * 64 + (lane & 15);
#pragma unroll
    for (int mf = 0; mf < 8; mf++) {
#pragma unroll
        for (int nf = 0; nf < 4; nf++) {
            int cc = c0 + nf * 16;
            float badd = bias[cc];
#pragma unroll
            for (int reg = 0; reg < 4; reg++)
                C[(size_t)(r0 + mf * 16 + reg) * ldc + cc] = acc[mf][nf][reg] + badd;
        }
    }
}

// ---------------------------------------------------------------------------
extern "C" void kernel_launch(void* const* d_in, const int* in_sizes, int n_in,
                              void* d_out, int out_size, void* d_ws, size_t ws_size,
                              hipStream_t stream) {
    const float* x    = (const float*)d_in[0];   // [4,2048,4096]
    const float* Wb   = (const float*)d_in[1];   // [4096,4096]
    const float* bias = (const float*)d_in[2];   // [4096]
    const float* Wr   = (const float*)d_in[3];   // [8,4096]
    const float* A    = (const float*)d_in[4];   // [8,16,4096]
    const float* Bm   = (const float*)d_in[5];   // [8,4096,16]
    float* out = (float*)d_out;

    char* p = (char*)d_ws;
    ushort_t* xcat = (ushort_t*)p; p += (size_t)T_TOK * KCAT * 2;   // 69.2 MB
    ushort_t* Wcat = (ushort_t*)p; p += (size_t)D_OUT * KCAT * 2;   // 34.6 MB
    ushort_t* Abf  = (ushort_t*)p; p += (size_t)(E_EXP * R_RANK) * D_IN * 2; // 1 MB
    int2*     eids = (int2*)p;     p += (size_t)T_TOK * sizeof(int2);
    float2*   wts  = (float2*)p;   p += (size_t)T_TOK * sizeof(float2);

    build_weights<<<D_OUT + E_EXP * R_RANK, 256, 0, stream>>>(Wb, Bm, A, Wcat, Abf);
    router_convert<<<T_TOK / 16, 256, 0, stream>>>(x, Wr, xcat, eids, wts);
    // h = xcat[:, :4096] @ Abf^T, scaled+masked, written into xcat cols 4096+
    h_gemm_v<<<T_TOK / 32, 256, 0, stream>>>(Abf, eids, wts, xcat);
    // out[8192,4096] = xcat @ Wcat^T + bias  (K = 4224 includes LoRA fold)
    gemm_bt_main<<<(T_TOK / 256) * (D_OUT / 256), 512, 0, stream>>>(xcat, Wcat, out, bias);
}